// Round 1
// baseline (846.713 us; speedup 1.0000x reference)
//
#include <hip/hip_runtime.h>
#include <hip/hip_bf16.h>

#define N_NODES 50000
#define N_EDGES 800000
#define FDIM 128
#define CDIM 64
#define NGRAPH 256
#define LRELU_SLOPE 0.2f

// ---------------------------------------------------------------- utilities
__device__ __forceinline__ float wave_sum(float v) {
#pragma unroll
    for (int off = 32; off >= 1; off >>= 1) v += __shfl_xor(v, off);
    return v;
}

// ---------------------------------------------------------------- CSR build
__global__ void k_hist(const int* __restrict__ dst, int* __restrict__ cnt) {
    int e = blockIdx.x * 256 + threadIdx.x;
    if (e < N_EDGES) atomicAdd(&cnt[dst[e]], 1);
}

__global__ void k_scan(const int* __restrict__ cnt, int* __restrict__ rowptr,
                       int* __restrict__ cursor) {
    __shared__ int buf[1024];
    __shared__ int s_carry;
    int tid = threadIdx.x;
    if (tid == 0) s_carry = 0;
    __syncthreads();
    for (int base = 0; base < N_NODES; base += 1024) {
        int idx = base + tid;
        int v = (idx < N_NODES) ? cnt[idx] : 0;
        buf[tid] = v;
        __syncthreads();
        for (int off = 1; off < 1024; off <<= 1) {
            int t = (tid >= off) ? buf[tid - off] : 0;
            __syncthreads();
            buf[tid] += t;
            __syncthreads();
        }
        int carry = s_carry;
        int excl = carry + buf[tid] - v;
        if (idx < N_NODES) { rowptr[idx] = excl; cursor[idx] = excl; }
        __syncthreads();
        if (tid == 1023) s_carry = carry + buf[1023];
        __syncthreads();
    }
    if (tid == 0) rowptr[N_NODES] = N_EDGES;
}

__global__ void k_scatter(const int* __restrict__ src, const int* __restrict__ dst,
                          int* __restrict__ cursor, int* __restrict__ csr_src) {
    int e = blockIdx.x * 256 + threadIdx.x;
    if (e < N_EDGES) {
        int d = dst[e];
        int pos = atomicAdd(&cursor[d], 1);
        csr_src[pos] = src[e];
    }
}

// ---------------------------------------------------------------- dual GEMM: xl = x@wl.T+bl, xr = x@wr.T+br
// block: 256 threads; 64 rows x 128 cols (cols 0..63 -> xl, 64..127 -> xr); BK=16
template <int K>
__global__ void k_gemm_dual(const float* __restrict__ x,
                            const float* __restrict__ wl, const float* __restrict__ bl,
                            const float* __restrict__ wr, const float* __restrict__ br,
                            float* __restrict__ xl, float* __restrict__ xr) {
    __shared__ float xs[16][68];
    __shared__ float wsh[16][132];
    int tid = threadIdx.x;
    int rowBase = blockIdx.x * 64;
    int tr = tid >> 4;   // 0..15 row group (4 rows each)
    int tc = tid & 15;   // 0..15 col group (8 cols each)
    float acc[4][8];
#pragma unroll
    for (int i = 0; i < 4; i++)
#pragma unroll
        for (int j = 0; j < 8; j++) acc[i][j] = 0.f;

    for (int k0 = 0; k0 < K; k0 += 16) {
        {   // stage x tile: 64 rows x 16 k
            int row = tid >> 2;
            int kk0 = (tid & 3) * 4;
            int grow = rowBase + row;
            float4 v = make_float4(0.f, 0.f, 0.f, 0.f);
            if (grow < N_NODES)
                v = *reinterpret_cast<const float4*>(&x[(size_t)grow * K + k0 + kk0]);
            xs[kk0 + 0][row] = v.x; xs[kk0 + 1][row] = v.y;
            xs[kk0 + 2][row] = v.z; xs[kk0 + 3][row] = v.w;
        }
        {   // stage weight tile: 128 cols x 16 k
            int col = tid >> 1;
            int kk0 = (tid & 1) * 8;
            const float* wp = (col < 64) ? wl : wr;
            int c = col & 63;
            float4 v0 = *reinterpret_cast<const float4*>(&wp[c * K + k0 + kk0]);
            float4 v1 = *reinterpret_cast<const float4*>(&wp[c * K + k0 + kk0 + 4]);
            wsh[kk0 + 0][col] = v0.x; wsh[kk0 + 1][col] = v0.y;
            wsh[kk0 + 2][col] = v0.z; wsh[kk0 + 3][col] = v0.w;
            wsh[kk0 + 4][col] = v1.x; wsh[kk0 + 5][col] = v1.y;
            wsh[kk0 + 6][col] = v1.z; wsh[kk0 + 7][col] = v1.w;
        }
        __syncthreads();
#pragma unroll
        for (int kk = 0; kk < 16; kk++) {
            float a[4], b[8];
#pragma unroll
            for (int i = 0; i < 4; i++) a[i] = xs[kk][tr * 4 + i];
#pragma unroll
            for (int j = 0; j < 8; j++) b[j] = wsh[kk][tc * 8 + j];
#pragma unroll
            for (int i = 0; i < 4; i++)
#pragma unroll
                for (int j = 0; j < 8; j++) acc[i][j] += a[i] * b[j];
        }
        __syncthreads();
    }
#pragma unroll
    for (int j = 0; j < 8; j++) {
        int col = tc * 8 + j;
        float bias = (col < 64) ? bl[col] : br[col - 64];
        float* outp = (col < 64) ? xl : xr;
        int c = col & 63;
#pragma unroll
        for (int i = 0; i < 4; i++) {
            int row = rowBase + tr * 4 + i;
            if (row < N_NODES) outp[(size_t)row * 64 + c] = acc[i][j] + bias;
        }
    }
}

// ---------------------------------------------------------------- GATv2 aggregate: one wave per dst node
__global__ void k_gat(const float* __restrict__ xl, const float* __restrict__ xr,
                      const int* __restrict__ rowptr, const int* __restrict__ csr_src,
                      const float* __restrict__ att, const float* __restrict__ bo,
                      float* __restrict__ e_scr, float* __restrict__ xout) {
    int wid = blockIdx.x * 4 + (threadIdx.x >> 6);
    int lane = threadIdx.x & 63;
    if (wid >= N_NODES) return;
    float attv = att[lane];
    float xrv = xr[(size_t)wid * 64 + lane];
    float xls = xl[(size_t)wid * 64 + lane];
    int beg = rowptr[wid], end = rowptr[wid + 1];

    // self-loop edge
    float s = xls + xrv;
    float t = (s > 0.f ? s : LRELU_SLOPE * s) * attv;
    float e_self = wave_sum(t);
    float m = e_self;
    float ssum = 1.0f;  // exp(e_self - m)

    // pass 1: scores + online softmax stats
    for (int j = beg; j < end; j++) {
        int sj = csr_src[j];
        float xlv = xl[(size_t)sj * 64 + lane];
        float s2 = xlv + xrv;
        float t2 = (s2 > 0.f ? s2 : LRELU_SLOPE * s2) * attv;
        float e = wave_sum(t2);
        e_scr[j] = e;
        if (e > m) {
            ssum = ssum * __expf(m - e) + 1.0f;
            m = e;
        } else {
            ssum += __expf(e - m);
        }
    }

    // pass 2: weighted aggregation
    float acc = __expf(e_self - m) * xls;
    for (int j = beg; j < end; j++) {
        int sj = csr_src[j];
        float xlv = xl[(size_t)sj * 64 + lane];
        float a = __expf(e_scr[j] - m);
        acc += a * xlv;
    }
    float o = acc / (ssum + 1e-16f) + bo[lane];
    xout[(size_t)wid * 64 + lane] = o > 0.f ? o : 0.f;
}

// ---------------------------------------------------------------- h = relu(concat(x1,x2,x3) @ lin1_w.T + b)
__global__ void k_gemm_h(const float* __restrict__ x1, const float* __restrict__ x2,
                         const float* __restrict__ x3, const float* __restrict__ w,
                         const float* __restrict__ b, float* __restrict__ h) {
    __shared__ float xs[16][68];
    __shared__ float wsh[16][68];
    int tid = threadIdx.x;
    int rowBase = blockIdx.x * 64;
    int tr = tid >> 4;  // 4 rows each
    int tc = tid & 15;  // 4 cols each
    float acc[4][4];
#pragma unroll
    for (int i = 0; i < 4; i++)
#pragma unroll
        for (int j = 0; j < 4; j++) acc[i][j] = 0.f;

    for (int k0 = 0; k0 < 192; k0 += 16) {
        const float* xp = (k0 < 64) ? x1 : (k0 < 128 ? x2 : x3);
        int kc = k0 & 63;
        {
            int row = tid >> 2;
            int kk0 = (tid & 3) * 4;
            int grow = rowBase + row;
            float4 v = make_float4(0.f, 0.f, 0.f, 0.f);
            if (grow < N_NODES)
                v = *reinterpret_cast<const float4*>(&xp[(size_t)grow * 64 + kc + kk0]);
            xs[kk0 + 0][row] = v.x; xs[kk0 + 1][row] = v.y;
            xs[kk0 + 2][row] = v.z; xs[kk0 + 3][row] = v.w;
        }
        {
            int col = tid >> 2;
            int kk0 = (tid & 3) * 4;
            float4 v = *reinterpret_cast<const float4*>(&w[col * 192 + k0 + kk0]);
            wsh[kk0 + 0][col] = v.x; wsh[kk0 + 1][col] = v.y;
            wsh[kk0 + 2][col] = v.z; wsh[kk0 + 3][col] = v.w;
        }
        __syncthreads();
#pragma unroll
        for (int kk = 0; kk < 16; kk++) {
            float a[4], bb[4];
#pragma unroll
            for (int i = 0; i < 4; i++) a[i] = xs[kk][tr * 4 + i];
#pragma unroll
            for (int j = 0; j < 4; j++) bb[j] = wsh[kk][tc * 4 + j];
#pragma unroll
            for (int i = 0; i < 4; i++)
#pragma unroll
                for (int j = 0; j < 4; j++) acc[i][j] += a[i] * bb[j];
        }
        __syncthreads();
    }
#pragma unroll
    for (int j = 0; j < 4; j++) {
        int col = tc * 4 + j;
        float bias = b[col];
#pragma unroll
        for (int i = 0; i < 4; i++) {
            int row = rowBase + tr * 4 + i;
            if (row < N_NODES) {
                float o = acc[i][j] + bias;
                h[(size_t)row * 64 + col] = o > 0.f ? o : 0.f;
            }
        }
    }
}

// ---------------------------------------------------------------- global_add_pool (batch_idx sorted)
__global__ void k_pool(const float* __restrict__ h, const int* __restrict__ batch,
                       float* __restrict__ g) {
    __shared__ float red[4][64];
    int base = blockIdx.x * 32;
    if (base >= N_NODES) return;
    int tid = threadIdx.x;
    int c = tid & 63;
    int rr = tid >> 6;
    int lastIdx = min(base + 31, N_NODES - 1);
    int b0 = batch[base];
    bool uniform = (batch[lastIdx] == b0);
    if (uniform) {
        float acc = 0.f;
        for (int r = rr; r < 32; r += 4) {
            int i = base + r;
            if (i < N_NODES) acc += h[(size_t)i * 64 + c];
        }
        red[rr][c] = acc;
        __syncthreads();
        if (rr == 0) {
            float sum = red[0][c] + red[1][c] + red[2][c] + red[3][c];
            atomicAdd(&g[b0 * 64 + c], sum);
        }
    } else {
        for (int r = rr; r < 32; r += 4) {
            int i = base + r;
            if (i < N_NODES) atomicAdd(&g[batch[i] * 64 + c], h[(size_t)i * 64 + c]);
        }
    }
}

// ---------------------------------------------------------------- heads: emb = relu(g@pred_w.T+pred_b); out = emb@cls_w.T+cls_b
__global__ void k_head(const float* __restrict__ g, const float* __restrict__ pw,
                       const float* __restrict__ pb, const float* __restrict__ cw,
                       const float* __restrict__ cb, float* __restrict__ out) {
    int t = threadIdx.x;  // one thread per graph
    float gr[64];
#pragma unroll
    for (int k = 0; k < 64; k++) gr[k] = g[t * 64 + k];
    float o0 = 0.f, o1 = 0.f;
    for (int c = 0; c < 64; c++) {
        float a = pb[c];
#pragma unroll
        for (int k = 0; k < 64; k++) a += gr[k] * pw[c * 64 + k];
        a = a > 0.f ? a : 0.f;
        o0 += a * cw[c];
        o1 += a * cw[64 + c];
    }
    out[t * 2 + 0] = o0 + cb[0];
    out[t * 2 + 1] = o1 + cb[1];
}

// ---------------------------------------------------------------- launcher
extern "C" void kernel_launch(void* const* d_in, const int* in_sizes, int n_in,
                              void* d_out, int out_size, void* d_ws, size_t ws_size,
                              hipStream_t stream) {
    const float* x    = (const float*)d_in[0];
    const int*   ei   = (const int*)d_in[1];
    const int*   bidx = (const int*)d_in[2];
    const float* wl1 = (const float*)d_in[3],  *bl1 = (const float*)d_in[4];
    const float* wr1 = (const float*)d_in[5],  *br1 = (const float*)d_in[6];
    const float* att1 = (const float*)d_in[7], *bo1 = (const float*)d_in[8];
    const float* wl2 = (const float*)d_in[9],  *bl2 = (const float*)d_in[10];
    const float* wr2 = (const float*)d_in[11], *br2 = (const float*)d_in[12];
    const float* att2 = (const float*)d_in[13], *bo2 = (const float*)d_in[14];
    const float* wl3 = (const float*)d_in[15], *bl3 = (const float*)d_in[16];
    const float* wr3 = (const float*)d_in[17], *br3 = (const float*)d_in[18];
    const float* att3 = (const float*)d_in[19], *bo3 = (const float*)d_in[20];
    const float* lw = (const float*)d_in[21], *lb = (const float*)d_in[22];
    const float* pw = (const float*)d_in[23], *pb = (const float*)d_in[24];
    const float* cw = (const float*)d_in[25], *cb = (const float*)d_in[26];
    float* out = (float*)d_out;

    char* wsb = (char*)d_ws;
    size_t off = 0;
    auto alloc = [&](size_t bytes) {
        void* p = wsb + off;
        off = (off + bytes + 255) & ~(size_t)255;
        return p;
    };
    int* cnt      = (int*)alloc((size_t)N_NODES * 4);
    int* rowptr   = (int*)alloc((size_t)(N_NODES + 1) * 4);
    int* cursor   = (int*)alloc((size_t)N_NODES * 4);
    int* csr_src  = (int*)alloc((size_t)N_EDGES * 4);
    float* e_scr  = (float*)alloc((size_t)N_EDGES * 4);
    float* xl     = (float*)alloc((size_t)N_NODES * 64 * 4);
    float* xrr    = (float*)alloc((size_t)N_NODES * 64 * 4);
    float* x1b    = (float*)alloc((size_t)N_NODES * 64 * 4);
    float* x2b    = (float*)alloc((size_t)N_NODES * 64 * 4);
    float* x3b    = (float*)alloc((size_t)N_NODES * 64 * 4);
    float* hb     = (float*)alloc((size_t)N_NODES * 64 * 4);
    float* g      = (float*)alloc((size_t)NGRAPH * 64 * 4);
    (void)ws_size; (void)in_sizes; (void)n_in; (void)out_size;

    const int* srcp = ei;
    const int* dstp = ei + N_EDGES;

    hipMemsetAsync(cnt, 0, (size_t)N_NODES * 4, stream);
    hipMemsetAsync(g, 0, (size_t)NGRAPH * 64 * 4, stream);

    k_hist<<<N_EDGES / 256, 256, 0, stream>>>(dstp, cnt);
    k_scan<<<1, 1024, 0, stream>>>(cnt, rowptr, cursor);
    k_scatter<<<N_EDGES / 256, 256, 0, stream>>>(srcp, dstp, cursor, csr_src);

    int gemmBlocks = (N_NODES + 63) / 64;
    int gatBlocks = (N_NODES + 3) / 4;

    // layer 1
    k_gemm_dual<128><<<gemmBlocks, 256, 0, stream>>>(x, wl1, bl1, wr1, br1, xl, xrr);
    k_gat<<<gatBlocks, 256, 0, stream>>>(xl, xrr, rowptr, csr_src, att1, bo1, e_scr, x1b);
    // layer 2
    k_gemm_dual<64><<<gemmBlocks, 256, 0, stream>>>(x1b, wl2, bl2, wr2, br2, xl, xrr);
    k_gat<<<gatBlocks, 256, 0, stream>>>(xl, xrr, rowptr, csr_src, att2, bo2, e_scr, x2b);
    // layer 3
    k_gemm_dual<64><<<gemmBlocks, 256, 0, stream>>>(x2b, wl3, bl3, wr3, br3, xl, xrr);
    k_gat<<<gatBlocks, 256, 0, stream>>>(xl, xrr, rowptr, csr_src, att3, bo3, e_scr, x3b);

    // head
    k_gemm_h<<<gemmBlocks, 256, 0, stream>>>(x1b, x2b, x3b, lw, lb, hb);
    k_pool<<<(N_NODES + 31) / 32, 256, 0, stream>>>(hb, bidx, g);
    k_head<<<1, 256, 0, stream>>>(g, pw, pb, cw, cb, out);
}

// Round 2
// 553.837 us; speedup vs baseline: 1.5288x; 1.5288x over previous
//
#include <hip/hip_runtime.h>
#include <hip/hip_bf16.h>

#define N_NODES 50000
#define N_EDGES 800000
#define FDIM 128
#define CDIM 64
#define NGRAPH 256
#define LRELU_SLOPE 0.2f

// ---------------------------------------------------------------- utilities
__device__ __forceinline__ float wave_sum(float v) {
#pragma unroll
    for (int off = 32; off >= 1; off >>= 1) v += __shfl_xor(v, off);
    return v;
}

// 4 independent butterfly reductions, interleaved for ILP on the DS chain
__device__ __forceinline__ void wave_sum4(float& a, float& b, float& c, float& d) {
#pragma unroll
    for (int off = 32; off >= 1; off >>= 1) {
        a += __shfl_xor(a, off);
        b += __shfl_xor(b, off);
        c += __shfl_xor(c, off);
        d += __shfl_xor(d, off);
    }
}

// ---------------------------------------------------------------- CSR build
__global__ void k_hist(const int* __restrict__ dst, int* __restrict__ cnt) {
    int e = blockIdx.x * 256 + threadIdx.x;
    if (e < N_EDGES) atomicAdd(&cnt[dst[e]], 1);
}

__global__ void k_scan(const int* __restrict__ cnt, int* __restrict__ rowptr,
                       int* __restrict__ cursor) {
    __shared__ int buf[1024];
    __shared__ int s_carry;
    int tid = threadIdx.x;
    if (tid == 0) s_carry = 0;
    __syncthreads();
    for (int base = 0; base < N_NODES; base += 1024) {
        int idx = base + tid;
        int v = (idx < N_NODES) ? cnt[idx] : 0;
        buf[tid] = v;
        __syncthreads();
        for (int off = 1; off < 1024; off <<= 1) {
            int t = (tid >= off) ? buf[tid - off] : 0;
            __syncthreads();
            buf[tid] += t;
            __syncthreads();
        }
        int carry = s_carry;
        int excl = carry + buf[tid] - v;
        if (idx < N_NODES) { rowptr[idx] = excl; cursor[idx] = excl; }
        __syncthreads();
        if (tid == 1023) s_carry = carry + buf[1023];
        __syncthreads();
    }
    if (tid == 0) rowptr[N_NODES] = N_EDGES;
}

__global__ void k_scatter(const int* __restrict__ src, const int* __restrict__ dst,
                          int* __restrict__ cursor, int* __restrict__ csr_src) {
    int e = blockIdx.x * 256 + threadIdx.x;
    if (e < N_EDGES) {
        int d = dst[e];
        int pos = atomicAdd(&cursor[d], 1);
        csr_src[pos] = src[e];
    }
}

// ---------------------------------------------------------------- dual GEMM: xl = x@wl.T+bl, xr = x@wr.T+br
// block: 256 threads; 64 rows x 128 cols (cols 0..63 -> xl, 64..127 -> xr); BK=16
template <int K>
__global__ void k_gemm_dual(const float* __restrict__ x,
                            const float* __restrict__ wl, const float* __restrict__ bl,
                            const float* __restrict__ wr, const float* __restrict__ br,
                            float* __restrict__ xl, float* __restrict__ xr) {
    __shared__ float xs[16][68];
    __shared__ float wsh[16][132];
    int tid = threadIdx.x;
    int rowBase = blockIdx.x * 64;
    int tr = tid >> 4;   // 0..15 row group (4 rows each)
    int tc = tid & 15;   // 0..15 col group (8 cols each)
    float acc[4][8];
#pragma unroll
    for (int i = 0; i < 4; i++)
#pragma unroll
        for (int j = 0; j < 8; j++) acc[i][j] = 0.f;

    for (int k0 = 0; k0 < K; k0 += 16) {
        {   // stage x tile: 64 rows x 16 k
            int row = tid >> 2;
            int kk0 = (tid & 3) * 4;
            int grow = rowBase + row;
            float4 v = make_float4(0.f, 0.f, 0.f, 0.f);
            if (grow < N_NODES)
                v = *reinterpret_cast<const float4*>(&x[(size_t)grow * K + k0 + kk0]);
            xs[kk0 + 0][row] = v.x; xs[kk0 + 1][row] = v.y;
            xs[kk0 + 2][row] = v.z; xs[kk0 + 3][row] = v.w;
        }
        {   // stage weight tile: 128 cols x 16 k
            int col = tid >> 1;
            int kk0 = (tid & 1) * 8;
            const float* wp = (col < 64) ? wl : wr;
            int c = col & 63;
            float4 v0 = *reinterpret_cast<const float4*>(&wp[c * K + k0 + kk0]);
            float4 v1 = *reinterpret_cast<const float4*>(&wp[c * K + k0 + kk0 + 4]);
            wsh[kk0 + 0][col] = v0.x; wsh[kk0 + 1][col] = v0.y;
            wsh[kk0 + 2][col] = v0.z; wsh[kk0 + 3][col] = v0.w;
            wsh[kk0 + 4][col] = v1.x; wsh[kk0 + 5][col] = v1.y;
            wsh[kk0 + 6][col] = v1.z; wsh[kk0 + 7][col] = v1.w;
        }
        __syncthreads();
#pragma unroll
        for (int kk = 0; kk < 16; kk++) {
            float a[4], b[8];
#pragma unroll
            for (int i = 0; i < 4; i++) a[i] = xs[kk][tr * 4 + i];
#pragma unroll
            for (int j = 0; j < 8; j++) b[j] = wsh[kk][tc * 8 + j];
#pragma unroll
            for (int i = 0; i < 4; i++)
#pragma unroll
                for (int j = 0; j < 8; j++) acc[i][j] += a[i] * b[j];
        }
        __syncthreads();
    }
#pragma unroll
    for (int j = 0; j < 8; j++) {
        int col = tc * 8 + j;
        float bias = (col < 64) ? bl[col] : br[col - 64];
        float* outp = (col < 64) ? xl : xr;
        int c = col & 63;
#pragma unroll
        for (int i = 0; i < 4; i++) {
            int row = rowBase + tr * 4 + i;
            if (row < N_NODES) outp[(size_t)row * 64 + c] = acc[i][j] + bias;
        }
    }
}

// ---------------------------------------------------------------- GATv2 aggregate: one wave per dst node
// Single-pass online softmax (flash-style), edge loop unrolled x4 for ILP.
__global__ void k_gat(const float* __restrict__ xl, const float* __restrict__ xr,
                      const int* __restrict__ rowptr, const int* __restrict__ csr_src,
                      const float* __restrict__ att, const float* __restrict__ bo,
                      float* __restrict__ xout) {
    int wid = blockIdx.x * 4 + (threadIdx.x >> 6);
    int lane = threadIdx.x & 63;
    if (wid >= N_NODES) return;
    float attv = att[lane];
    float xrv = xr[(size_t)wid * 64 + lane];
    float xls = xl[(size_t)wid * 64 + lane];
    int beg = rowptr[wid], end = rowptr[wid + 1];

    // self-loop edge initializes the online state
    float s = xls + xrv;
    float t = (s > 0.f ? s : LRELU_SLOPE * s) * attv;
    float m = wave_sum(t);
    float ssum = 1.0f;   // exp(m - m)
    float acc = xls;     // exp(m - m) * xls

    // branchless online update: mn = max(m,e); rescale running state
    auto upd = [&](float e, float v) {
        float mn = fmaxf(m, e);
        float sc = __expf(m - mn);   // 1.0 when max unchanged
        float w  = __expf(e - mn);
        ssum = ssum * sc + w;
        acc  = acc  * sc + w * v;
        m = mn;
    };

    int j = beg;
    for (; j + 4 <= end; j += 4) {
        int s0 = csr_src[j + 0], s1 = csr_src[j + 1];
        int s2 = csr_src[j + 2], s3 = csr_src[j + 3];
        float v0 = xl[(size_t)s0 * 64 + lane];
        float v1 = xl[(size_t)s1 * 64 + lane];
        float v2 = xl[(size_t)s2 * 64 + lane];
        float v3 = xl[(size_t)s3 * 64 + lane];
        float a0 = v0 + xrv, a1 = v1 + xrv, a2 = v2 + xrv, a3 = v3 + xrv;
        float t0 = (a0 > 0.f ? a0 : LRELU_SLOPE * a0) * attv;
        float t1 = (a1 > 0.f ? a1 : LRELU_SLOPE * a1) * attv;
        float t2 = (a2 > 0.f ? a2 : LRELU_SLOPE * a2) * attv;
        float t3 = (a3 > 0.f ? a3 : LRELU_SLOPE * a3) * attv;
        wave_sum4(t0, t1, t2, t3);
        upd(t0, v0); upd(t1, v1); upd(t2, v2); upd(t3, v3);
    }
    for (; j < end; j++) {
        int sj = csr_src[j];
        float v = xl[(size_t)sj * 64 + lane];
        float a = v + xrv;
        float tt = (a > 0.f ? a : LRELU_SLOPE * a) * attv;
        float e = wave_sum(tt);
        upd(e, v);
    }

    float o = acc / (ssum + 1e-16f) + bo[lane];
    xout[(size_t)wid * 64 + lane] = o > 0.f ? o : 0.f;
}

// ---------------------------------------------------------------- h = relu(concat(x1,x2,x3) @ lin1_w.T + b)
__global__ void k_gemm_h(const float* __restrict__ x1, const float* __restrict__ x2,
                         const float* __restrict__ x3, const float* __restrict__ w,
                         const float* __restrict__ b, float* __restrict__ h) {
    __shared__ float xs[16][68];
    __shared__ float wsh[16][68];
    int tid = threadIdx.x;
    int rowBase = blockIdx.x * 64;
    int tr = tid >> 4;  // 4 rows each
    int tc = tid & 15;  // 4 cols each
    float acc[4][4];
#pragma unroll
    for (int i = 0; i < 4; i++)
#pragma unroll
        for (int j = 0; j < 4; j++) acc[i][j] = 0.f;

    for (int k0 = 0; k0 < 192; k0 += 16) {
        const float* xp = (k0 < 64) ? x1 : (k0 < 128 ? x2 : x3);
        int kc = k0 & 63;
        {
            int row = tid >> 2;
            int kk0 = (tid & 3) * 4;
            int grow = rowBase + row;
            float4 v = make_float4(0.f, 0.f, 0.f, 0.f);
            if (grow < N_NODES)
                v = *reinterpret_cast<const float4*>(&xp[(size_t)grow * 64 + kc + kk0]);
            xs[kk0 + 0][row] = v.x; xs[kk0 + 1][row] = v.y;
            xs[kk0 + 2][row] = v.z; xs[kk0 + 3][row] = v.w;
        }
        {
            int col = tid >> 2;
            int kk0 = (tid & 3) * 4;
            float4 v = *reinterpret_cast<const float4*>(&w[col * 192 + k0 + kk0]);
            wsh[kk0 + 0][col] = v.x; wsh[kk0 + 1][col] = v.y;
            wsh[kk0 + 2][col] = v.z; wsh[kk0 + 3][col] = v.w;
        }
        __syncthreads();
#pragma unroll
        for (int kk = 0; kk < 16; kk++) {
            float a[4], bb[4];
#pragma unroll
            for (int i = 0; i < 4; i++) a[i] = xs[kk][tr * 4 + i];
#pragma unroll
            for (int j = 0; j < 4; j++) bb[j] = wsh[kk][tc * 4 + j];
#pragma unroll
            for (int i = 0; i < 4; i++)
#pragma unroll
                for (int j = 0; j < 4; j++) acc[i][j] += a[i] * bb[j];
        }
        __syncthreads();
    }
#pragma unroll
    for (int j = 0; j < 4; j++) {
        int col = tc * 4 + j;
        float bias = b[col];
#pragma unroll
        for (int i = 0; i < 4; i++) {
            int row = rowBase + tr * 4 + i;
            if (row < N_NODES) {
                float o = acc[i][j] + bias;
                h[(size_t)row * 64 + col] = o > 0.f ? o : 0.f;
            }
        }
    }
}

// ---------------------------------------------------------------- global_add_pool (batch_idx sorted)
__global__ void k_pool(const float* __restrict__ h, const int* __restrict__ batch,
                       float* __restrict__ g) {
    __shared__ float red[4][64];
    int base = blockIdx.x * 32;
    if (base >= N_NODES) return;
    int tid = threadIdx.x;
    int c = tid & 63;
    int rr = tid >> 6;
    int lastIdx = min(base + 31, N_NODES - 1);
    int b0 = batch[base];
    bool uniform = (batch[lastIdx] == b0);
    if (uniform) {
        float acc = 0.f;
        for (int r = rr; r < 32; r += 4) {
            int i = base + r;
            if (i < N_NODES) acc += h[(size_t)i * 64 + c];
        }
        red[rr][c] = acc;
        __syncthreads();
        if (rr == 0) {
            float sum = red[0][c] + red[1][c] + red[2][c] + red[3][c];
            atomicAdd(&g[b0 * 64 + c], sum);
        }
    } else {
        for (int r = rr; r < 32; r += 4) {
            int i = base + r;
            if (i < N_NODES) atomicAdd(&g[batch[i] * 64 + c], h[(size_t)i * 64 + c]);
        }
    }
}

// ---------------------------------------------------------------- heads: emb = relu(g@pred_w.T+pred_b); out = emb@cls_w.T+cls_b
__global__ void k_head(const float* __restrict__ g, const float* __restrict__ pw,
                       const float* __restrict__ pb, const float* __restrict__ cw,
                       const float* __restrict__ cb, float* __restrict__ out) {
    int t = threadIdx.x;  // one thread per graph
    float gr[64];
#pragma unroll
    for (int k = 0; k < 64; k++) gr[k] = g[t * 64 + k];
    float o0 = 0.f, o1 = 0.f;
    for (int c = 0; c < 64; c++) {
        float a = pb[c];
#pragma unroll
        for (int k = 0; k < 64; k++) a += gr[k] * pw[c * 64 + k];
        a = a > 0.f ? a : 0.f;
        o0 += a * cw[c];
        o1 += a * cw[64 + c];
    }
    out[t * 2 + 0] = o0 + cb[0];
    out[t * 2 + 1] = o1 + cb[1];
}

// ---------------------------------------------------------------- launcher
extern "C" void kernel_launch(void* const* d_in, const int* in_sizes, int n_in,
                              void* d_out, int out_size, void* d_ws, size_t ws_size,
                              hipStream_t stream) {
    const float* x    = (const float*)d_in[0];
    const int*   ei   = (const int*)d_in[1];
    const int*   bidx = (const int*)d_in[2];
    const float* wl1 = (const float*)d_in[3],  *bl1 = (const float*)d_in[4];
    const float* wr1 = (const float*)d_in[5],  *br1 = (const float*)d_in[6];
    const float* att1 = (const float*)d_in[7], *bo1 = (const float*)d_in[8];
    const float* wl2 = (const float*)d_in[9],  *bl2 = (const float*)d_in[10];
    const float* wr2 = (const float*)d_in[11], *br2 = (const float*)d_in[12];
    const float* att2 = (const float*)d_in[13], *bo2 = (const float*)d_in[14];
    const float* wl3 = (const float*)d_in[15], *bl3 = (const float*)d_in[16];
    const float* wr3 = (const float*)d_in[17], *br3 = (const float*)d_in[18];
    const float* att3 = (const float*)d_in[19], *bo3 = (const float*)d_in[20];
    const float* lw = (const float*)d_in[21], *lb = (const float*)d_in[22];
    const float* pw = (const float*)d_in[23], *pb = (const float*)d_in[24];
    const float* cw = (const float*)d_in[25], *cb = (const float*)d_in[26];
    float* out = (float*)d_out;

    char* wsb = (char*)d_ws;
    size_t off = 0;
    auto alloc = [&](size_t bytes) {
        void* p = wsb + off;
        off = (off + bytes + 255) & ~(size_t)255;
        return p;
    };
    int* cnt      = (int*)alloc((size_t)N_NODES * 4);
    int* rowptr   = (int*)alloc((size_t)(N_NODES + 1) * 4);
    int* cursor   = (int*)alloc((size_t)N_NODES * 4);
    int* csr_src  = (int*)alloc((size_t)N_EDGES * 4);
    float* xl     = (float*)alloc((size_t)N_NODES * 64 * 4);
    float* xrr    = (float*)alloc((size_t)N_NODES * 64 * 4);
    float* x1b    = (float*)alloc((size_t)N_NODES * 64 * 4);
    float* x2b    = (float*)alloc((size_t)N_NODES * 64 * 4);
    float* x3b    = (float*)alloc((size_t)N_NODES * 64 * 4);
    float* hb     = (float*)alloc((size_t)N_NODES * 64 * 4);
    float* g      = (float*)alloc((size_t)NGRAPH * 64 * 4);
    (void)ws_size; (void)in_sizes; (void)n_in; (void)out_size;

    const int* srcp = ei;
    const int* dstp = ei + N_EDGES;

    hipMemsetAsync(cnt, 0, (size_t)N_NODES * 4, stream);
    hipMemsetAsync(g, 0, (size_t)NGRAPH * 64 * 4, stream);

    k_hist<<<N_EDGES / 256, 256, 0, stream>>>(dstp, cnt);
    k_scan<<<1, 1024, 0, stream>>>(cnt, rowptr, cursor);
    k_scatter<<<N_EDGES / 256, 256, 0, stream>>>(srcp, dstp, cursor, csr_src);

    int gemmBlocks = (N_NODES + 63) / 64;
    int gatBlocks = (N_NODES + 3) / 4;

    // layer 1
    k_gemm_dual<128><<<gemmBlocks, 256, 0, stream>>>(x, wl1, bl1, wr1, br1, xl, xrr);
    k_gat<<<gatBlocks, 256, 0, stream>>>(xl, xrr, rowptr, csr_src, att1, bo1, x1b);
    // layer 2
    k_gemm_dual<64><<<gemmBlocks, 256, 0, stream>>>(x1b, wl2, bl2, wr2, br2, xl, xrr);
    k_gat<<<gatBlocks, 256, 0, stream>>>(xl, xrr, rowptr, csr_src, att2, bo2, x2b);
    // layer 3
    k_gemm_dual<64><<<gemmBlocks, 256, 0, stream>>>(x2b, wl3, bl3, wr3, br3, xl, xrr);
    k_gat<<<gatBlocks, 256, 0, stream>>>(xl, xrr, rowptr, csr_src, att3, bo3, x3b);

    // head
    k_gemm_h<<<gemmBlocks, 256, 0, stream>>>(x1b, x2b, x3b, lw, lb, hb);
    k_pool<<<(N_NODES + 31) / 32, 256, 0, stream>>>(hb, bidx, g);
    k_head<<<1, 256, 0, stream>>>(g, pw, pb, cw, cb, out);
}

// Round 3
// 473.688 us; speedup vs baseline: 1.7875x; 1.1692x over previous
//
#include <hip/hip_runtime.h>
#include <hip/hip_bf16.h>

#define N_NODES 50000
#define N_EDGES 800000
#define FDIM 128
#define CDIM 64
#define NGRAPH 256
#define LRELU_SLOPE 0.2f
#define SCAN_NB ((N_NODES + 1023) / 1024)   // 49

// ---------------------------------------------------------------- utilities
__device__ __forceinline__ float wave_sum(float v) {
#pragma unroll
    for (int off = 32; off >= 1; off >>= 1) v += __shfl_xor(v, off);
    return v;
}

__device__ __forceinline__ void wave_sum4(float& a, float& b, float& c, float& d) {
#pragma unroll
    for (int off = 32; off >= 1; off >>= 1) {
        a += __shfl_xor(a, off);
        b += __shfl_xor(b, off);
        c += __shfl_xor(c, off);
        d += __shfl_xor(d, off);
    }
}

__device__ __forceinline__ int wave_incl_scan(int v, int lane) {
#pragma unroll
    for (int off = 1; off < 64; off <<= 1) {
        int t = __shfl_up(v, off);
        if (lane >= off) v += t;
    }
    return v;
}

// ---------------------------------------------------------------- CSR build
__global__ void k_hist(const int* __restrict__ dst, int* __restrict__ cnt) {
    int e = blockIdx.x * 256 + threadIdx.x;
    if (e < N_EDGES) atomicAdd(&cnt[dst[e]], 1);
}

// block-local exclusive scan (1024 elems/block) -> rowptr partials + block sums
__global__ void k_scan1(const int* __restrict__ cnt, int* __restrict__ rowptr,
                        int* __restrict__ blocksum) {
    __shared__ int wsum[16];
    int tid = threadIdx.x;
    int gid = blockIdx.x * 1024 + tid;
    int lane = tid & 63, wid = tid >> 6;
    int v = (gid < N_NODES) ? cnt[gid] : 0;
    int incl = wave_incl_scan(v, lane);
    if (lane == 63) wsum[wid] = incl;
    __syncthreads();
    if (wid == 0) {
        int wv = (lane < 16) ? wsum[lane] : 0;
        int wincl = wave_incl_scan(wv, lane);
        if (lane < 16) wsum[lane] = wincl - wv;  // exclusive wave offsets
    }
    __syncthreads();
    int excl = incl - v + wsum[wid];
    if (gid < N_NODES) rowptr[gid] = excl;
    if (tid == 1023) blocksum[blockIdx.x] = excl + v;
}

// scan the block sums (one wave)
__global__ void k_scan2(int* __restrict__ blocksum) {
    int lane = threadIdx.x;
    int v = (lane < SCAN_NB) ? blocksum[lane] : 0;
    int incl = wave_incl_scan(v, lane);
    if (lane < SCAN_NB) blocksum[lane] = incl - v;  // exclusive
}

// add block offsets, emit cursor, finalize rowptr[N]
__global__ void k_scan3(int* __restrict__ rowptr, const int* __restrict__ blocksum,
                        int* __restrict__ cursor) {
    int tid = threadIdx.x;
    int gid = blockIdx.x * 1024 + tid;
    if (gid < N_NODES) {
        int r = rowptr[gid] + blocksum[blockIdx.x];
        rowptr[gid] = r;
        cursor[gid] = r;
    }
    if (blockIdx.x == 0 && tid == 0) rowptr[N_NODES] = N_EDGES;
}

__global__ void k_scatter(const int* __restrict__ src, const int* __restrict__ dst,
                          int* __restrict__ cursor, int* __restrict__ csr_src) {
    int e = blockIdx.x * 256 + threadIdx.x;
    if (e < N_EDGES) {
        int d = dst[e];
        int pos = atomicAdd(&cursor[d], 1);
        csr_src[pos] = src[e];
    }
}

// ---------------------------------------------------------------- dual GEMM: xl = x@wl.T+bl, xr = x@wr.T+br
template <int K>
__global__ void k_gemm_dual(const float* __restrict__ x,
                            const float* __restrict__ wl, const float* __restrict__ bl,
                            const float* __restrict__ wr, const float* __restrict__ br,
                            float* __restrict__ xl, float* __restrict__ xr) {
    __shared__ float xs[16][68];
    __shared__ float wsh[16][132];
    int tid = threadIdx.x;
    int rowBase = blockIdx.x * 64;
    int tr = tid >> 4;   // 0..15 row group (4 rows each)
    int tc = tid & 15;   // 0..15 col group (8 cols each)
    float acc[4][8];
#pragma unroll
    for (int i = 0; i < 4; i++)
#pragma unroll
        for (int j = 0; j < 8; j++) acc[i][j] = 0.f;

    for (int k0 = 0; k0 < K; k0 += 16) {
        {
            int row = tid >> 2;
            int kk0 = (tid & 3) * 4;
            int grow = rowBase + row;
            float4 v = make_float4(0.f, 0.f, 0.f, 0.f);
            if (grow < N_NODES)
                v = *reinterpret_cast<const float4*>(&x[(size_t)grow * K + k0 + kk0]);
            xs[kk0 + 0][row] = v.x; xs[kk0 + 1][row] = v.y;
            xs[kk0 + 2][row] = v.z; xs[kk0 + 3][row] = v.w;
        }
        {
            int col = tid >> 1;
            int kk0 = (tid & 1) * 8;
            const float* wp = (col < 64) ? wl : wr;
            int c = col & 63;
            float4 v0 = *reinterpret_cast<const float4*>(&wp[c * K + k0 + kk0]);
            float4 v1 = *reinterpret_cast<const float4*>(&wp[c * K + k0 + kk0 + 4]);
            wsh[kk0 + 0][col] = v0.x; wsh[kk0 + 1][col] = v0.y;
            wsh[kk0 + 2][col] = v0.z; wsh[kk0 + 3][col] = v0.w;
            wsh[kk0 + 4][col] = v1.x; wsh[kk0 + 5][col] = v1.y;
            wsh[kk0 + 6][col] = v1.z; wsh[kk0 + 7][col] = v1.w;
        }
        __syncthreads();
#pragma unroll
        for (int kk = 0; kk < 16; kk++) {
            float a[4], b[8];
#pragma unroll
            for (int i = 0; i < 4; i++) a[i] = xs[kk][tr * 4 + i];
#pragma unroll
            for (int j = 0; j < 8; j++) b[j] = wsh[kk][tc * 8 + j];
#pragma unroll
            for (int i = 0; i < 4; i++)
#pragma unroll
                for (int j = 0; j < 8; j++) acc[i][j] += a[i] * b[j];
        }
        __syncthreads();
    }
#pragma unroll
    for (int j = 0; j < 8; j++) {
        int col = tc * 8 + j;
        float bias = (col < 64) ? bl[col] : br[col - 64];
        float* outp = (col < 64) ? xl : xr;
        int c = col & 63;
#pragma unroll
        for (int i = 0; i < 4; i++) {
            int row = rowBase + tr * 4 + i;
            if (row < N_NODES) outp[(size_t)row * 64 + c] = acc[i][j] + bias;
        }
    }
}

// ---------------------------------------------------------------- GATv2 aggregate: one wave per dst node
__global__ void k_gat(const float* __restrict__ xl, const float* __restrict__ xr,
                      const int* __restrict__ rowptr, const int* __restrict__ csr_src,
                      const float* __restrict__ att, const float* __restrict__ bo,
                      float* __restrict__ xout) {
    int wid = blockIdx.x * 4 + (threadIdx.x >> 6);
    int lane = threadIdx.x & 63;
    if (wid >= N_NODES) return;
    float attv = att[lane];
    float xrv = xr[(size_t)wid * 64 + lane];
    float xls = xl[(size_t)wid * 64 + lane];
    int beg = rowptr[wid], end = rowptr[wid + 1];

    float s = xls + xrv;
    float t = (s > 0.f ? s : LRELU_SLOPE * s) * attv;
    float m = wave_sum(t);
    float ssum = 1.0f;
    float acc = xls;

    auto upd = [&](float e, float v) {
        float mn = fmaxf(m, e);
        float sc = __expf(m - mn);
        float w  = __expf(e - mn);
        ssum = ssum * sc + w;
        acc  = acc  * sc + w * v;
        m = mn;
    };

    int j = beg;
    for (; j + 4 <= end; j += 4) {
        int s0 = csr_src[j + 0], s1 = csr_src[j + 1];
        int s2 = csr_src[j + 2], s3 = csr_src[j + 3];
        float v0 = xl[(size_t)s0 * 64 + lane];
        float v1 = xl[(size_t)s1 * 64 + lane];
        float v2 = xl[(size_t)s2 * 64 + lane];
        float v3 = xl[(size_t)s3 * 64 + lane];
        float a0 = v0 + xrv, a1 = v1 + xrv, a2 = v2 + xrv, a3 = v3 + xrv;
        float t0 = (a0 > 0.f ? a0 : LRELU_SLOPE * a0) * attv;
        float t1 = (a1 > 0.f ? a1 : LRELU_SLOPE * a1) * attv;
        float t2 = (a2 > 0.f ? a2 : LRELU_SLOPE * a2) * attv;
        float t3 = (a3 > 0.f ? a3 : LRELU_SLOPE * a3) * attv;
        wave_sum4(t0, t1, t2, t3);
        upd(t0, v0); upd(t1, v1); upd(t2, v2); upd(t3, v3);
    }
    for (; j < end; j++) {
        int sj = csr_src[j];
        float v = xl[(size_t)sj * 64 + lane];
        float a = v + xrv;
        float tt = (a > 0.f ? a : LRELU_SLOPE * a) * attv;
        float e = wave_sum(tt);
        upd(e, v);
    }

    float o = acc / (ssum + 1e-16f) + bo[lane];
    xout[(size_t)wid * 64 + lane] = o > 0.f ? o : 0.f;
}

// ---------------------------------------------------------------- h = relu(concat(x1,x2,x3) @ lin1_w.T + b)
__global__ void k_gemm_h(const float* __restrict__ x1, const float* __restrict__ x2,
                         const float* __restrict__ x3, const float* __restrict__ w,
                         const float* __restrict__ b, float* __restrict__ h) {
    __shared__ float xs[16][68];
    __shared__ float wsh[16][68];
    int tid = threadIdx.x;
    int rowBase = blockIdx.x * 64;
    int tr = tid >> 4;
    int tc = tid & 15;
    float acc[4][4];
#pragma unroll
    for (int i = 0; i < 4; i++)
#pragma unroll
        for (int j = 0; j < 4; j++) acc[i][j] = 0.f;

    for (int k0 = 0; k0 < 192; k0 += 16) {
        const float* xp = (k0 < 64) ? x1 : (k0 < 128 ? x2 : x3);
        int kc = k0 & 63;
        {
            int row = tid >> 2;
            int kk0 = (tid & 3) * 4;
            int grow = rowBase + row;
            float4 v = make_float4(0.f, 0.f, 0.f, 0.f);
            if (grow < N_NODES)
                v = *reinterpret_cast<const float4*>(&xp[(size_t)grow * 64 + kc + kk0]);
            xs[kk0 + 0][row] = v.x; xs[kk0 + 1][row] = v.y;
            xs[kk0 + 2][row] = v.z; xs[kk0 + 3][row] = v.w;
        }
        {
            int col = tid >> 2;
            int kk0 = (tid & 3) * 4;
            float4 v = *reinterpret_cast<const float4*>(&w[col * 192 + k0 + kk0]);
            wsh[kk0 + 0][col] = v.x; wsh[kk0 + 1][col] = v.y;
            wsh[kk0 + 2][col] = v.z; wsh[kk0 + 3][col] = v.w;
        }
        __syncthreads();
#pragma unroll
        for (int kk = 0; kk < 16; kk++) {
            float a[4], bb[4];
#pragma unroll
            for (int i = 0; i < 4; i++) a[i] = xs[kk][tr * 4 + i];
#pragma unroll
            for (int j = 0; j < 4; j++) bb[j] = wsh[kk][tc * 4 + j];
#pragma unroll
            for (int i = 0; i < 4; i++)
#pragma unroll
                for (int j = 0; j < 4; j++) acc[i][j] += a[i] * bb[j];
        }
        __syncthreads();
    }
#pragma unroll
    for (int j = 0; j < 4; j++) {
        int col = tc * 4 + j;
        float bias = b[col];
#pragma unroll
        for (int i = 0; i < 4; i++) {
            int row = rowBase + tr * 4 + i;
            if (row < N_NODES) {
                float o = acc[i][j] + bias;
                h[(size_t)row * 64 + col] = o > 0.f ? o : 0.f;
            }
        }
    }
}

// ---------------------------------------------------------------- global_add_pool (batch_idx sorted)
__global__ void k_pool(const float* __restrict__ h, const int* __restrict__ batch,
                       float* __restrict__ g) {
    __shared__ float red[4][64];
    int base = blockIdx.x * 32;
    if (base >= N_NODES) return;
    int tid = threadIdx.x;
    int c = tid & 63;
    int rr = tid >> 6;
    int lastIdx = min(base + 31, N_NODES - 1);
    int b0 = batch[base];
    bool uniform = (batch[lastIdx] == b0);
    if (uniform) {
        float acc = 0.f;
        for (int r = rr; r < 32; r += 4) {
            int i = base + r;
            if (i < N_NODES) acc += h[(size_t)i * 64 + c];
        }
        red[rr][c] = acc;
        __syncthreads();
        if (rr == 0) {
            float sum = red[0][c] + red[1][c] + red[2][c] + red[3][c];
            atomicAdd(&g[b0 * 64 + c], sum);
        }
    } else {
        for (int r = rr; r < 32; r += 4) {
            int i = base + r;
            if (i < N_NODES) atomicAdd(&g[batch[i] * 64 + c], h[(size_t)i * 64 + c]);
        }
    }
}

// ---------------------------------------------------------------- heads
__global__ void k_head(const float* __restrict__ g, const float* __restrict__ pw,
                       const float* __restrict__ pb, const float* __restrict__ cw,
                       const float* __restrict__ cb, float* __restrict__ out) {
    int t = threadIdx.x;
    float gr[64];
#pragma unroll
    for (int k = 0; k < 64; k++) gr[k] = g[t * 64 + k];
    float o0 = 0.f, o1 = 0.f;
    for (int c = 0; c < 64; c++) {
        float a = pb[c];
#pragma unroll
        for (int k = 0; k < 64; k++) a += gr[k] * pw[c * 64 + k];
        a = a > 0.f ? a : 0.f;
        o0 += a * cw[c];
        o1 += a * cw[64 + c];
    }
    out[t * 2 + 0] = o0 + cb[0];
    out[t * 2 + 1] = o1 + cb[1];
}

// ---------------------------------------------------------------- launcher
extern "C" void kernel_launch(void* const* d_in, const int* in_sizes, int n_in,
                              void* d_out, int out_size, void* d_ws, size_t ws_size,
                              hipStream_t stream) {
    const float* x    = (const float*)d_in[0];
    const int*   ei   = (const int*)d_in[1];
    const int*   bidx = (const int*)d_in[2];
    const float* wl1 = (const float*)d_in[3],  *bl1 = (const float*)d_in[4];
    const float* wr1 = (const float*)d_in[5],  *br1 = (const float*)d_in[6];
    const float* att1 = (const float*)d_in[7], *bo1 = (const float*)d_in[8];
    const float* wl2 = (const float*)d_in[9],  *bl2 = (const float*)d_in[10];
    const float* wr2 = (const float*)d_in[11], *br2 = (const float*)d_in[12];
    const float* att2 = (const float*)d_in[13], *bo2 = (const float*)d_in[14];
    const float* wl3 = (const float*)d_in[15], *bl3 = (const float*)d_in[16];
    const float* wr3 = (const float*)d_in[17], *br3 = (const float*)d_in[18];
    const float* att3 = (const float*)d_in[19], *bo3 = (const float*)d_in[20];
    const float* lw = (const float*)d_in[21], *lb = (const float*)d_in[22];
    const float* pw = (const float*)d_in[23], *pb = (const float*)d_in[24];
    const float* cw = (const float*)d_in[25], *cb = (const float*)d_in[26];
    float* out = (float*)d_out;

    char* wsb = (char*)d_ws;
    size_t off = 0;
    auto alloc = [&](size_t bytes) {
        void* p = wsb + off;
        off = (off + bytes + 255) & ~(size_t)255;
        return p;
    };
    int* cnt      = (int*)alloc((size_t)N_NODES * 4);
    int* rowptr   = (int*)alloc((size_t)(N_NODES + 1) * 4);
    int* cursor   = (int*)alloc((size_t)N_NODES * 4);
    int* blocksum = (int*)alloc((size_t)SCAN_NB * 4);
    int* csr_src  = (int*)alloc((size_t)N_EDGES * 4);
    float* xl     = (float*)alloc((size_t)N_NODES * 64 * 4);
    float* xrr    = (float*)alloc((size_t)N_NODES * 64 * 4);
    float* x1b    = (float*)alloc((size_t)N_NODES * 64 * 4);
    float* x2b    = (float*)alloc((size_t)N_NODES * 64 * 4);
    float* x3b    = (float*)alloc((size_t)N_NODES * 64 * 4);
    float* hb     = (float*)alloc((size_t)N_NODES * 64 * 4);
    float* g      = (float*)alloc((size_t)NGRAPH * 64 * 4);
    (void)ws_size; (void)in_sizes; (void)n_in; (void)out_size;

    const int* srcp = ei;
    const int* dstp = ei + N_EDGES;

    hipMemsetAsync(cnt, 0, (size_t)N_NODES * 4, stream);
    hipMemsetAsync(g, 0, (size_t)NGRAPH * 64 * 4, stream);

    k_hist<<<N_EDGES / 256, 256, 0, stream>>>(dstp, cnt);
    k_scan1<<<SCAN_NB, 1024, 0, stream>>>(cnt, rowptr, blocksum);
    k_scan2<<<1, 64, 0, stream>>>(blocksum);
    k_scan3<<<SCAN_NB, 1024, 0, stream>>>(rowptr, blocksum, cursor);
    k_scatter<<<N_EDGES / 256, 256, 0, stream>>>(srcp, dstp, cursor, csr_src);

    int gemmBlocks = (N_NODES + 63) / 64;
    int gatBlocks = (N_NODES + 3) / 4;

    // layer 1
    k_gemm_dual<128><<<gemmBlocks, 256, 0, stream>>>(x, wl1, bl1, wr1, br1, xl, xrr);
    k_gat<<<gatBlocks, 256, 0, stream>>>(xl, xrr, rowptr, csr_src, att1, bo1, x1b);
    // layer 2
    k_gemm_dual<64><<<gemmBlocks, 256, 0, stream>>>(x1b, wl2, bl2, wr2, br2, xl, xrr);
    k_gat<<<gatBlocks, 256, 0, stream>>>(xl, xrr, rowptr, csr_src, att2, bo2, x2b);
    // layer 3
    k_gemm_dual<64><<<gemmBlocks, 256, 0, stream>>>(x2b, wl3, bl3, wr3, br3, xl, xrr);
    k_gat<<<gatBlocks, 256, 0, stream>>>(xl, xrr, rowptr, csr_src, att3, bo3, x3b);

    // head
    k_gemm_h<<<gemmBlocks, 256, 0, stream>>>(x1b, x2b, x3b, lw, lb, hb);
    k_pool<<<(N_NODES + 31) / 32, 256, 0, stream>>>(hb, bidx, g);
    k_head<<<1, 256, 0, stream>>>(g, pw, pb, cw, cb, out);
}

// Round 4
// 375.795 us; speedup vs baseline: 2.2531x; 1.2605x over previous
//
#include <hip/hip_runtime.h>
#include <hip/hip_bf16.h>

#define N_NODES 50000
#define N_EDGES 800000
#define FDIM 128
#define CDIM 64
#define NGRAPH 256
#define LRELU_SLOPE 0.2f
#define SCAN_NB ((N_NODES + 1023) / 1024)   // 49

typedef unsigned short ushort_t;
typedef unsigned int uint_t;
typedef __attribute__((ext_vector_type(8))) short short8v;
typedef __attribute__((ext_vector_type(4))) float float4v;

// ---------------------------------------------------------------- bf16 helpers (RNE)
__device__ __forceinline__ ushort_t f2bf(float f) {
    uint_t u = __float_as_uint(f);
    u += 0x7FFFu + ((u >> 16) & 1u);
    return (ushort_t)(u >> 16);
}
__device__ __forceinline__ float bf2f(ushort_t u) {
    return __uint_as_float(((uint_t)u) << 16);
}

__device__ __forceinline__ float wave_sum(float v) {
#pragma unroll
    for (int off = 32; off >= 1; off >>= 1) v += __shfl_xor(v, off);
    return v;
}

__device__ __forceinline__ int wave_incl_scan(int v, int lane) {
#pragma unroll
    for (int off = 1; off < 64; off <<= 1) {
        int t = __shfl_up(v, off);
        if (lane >= off) v += t;
    }
    return v;
}

// ---------------------------------------------------------------- CSR build
__global__ void k_hist(const int* __restrict__ dst, int* __restrict__ cnt) {
    int e = blockIdx.x * 256 + threadIdx.x;
    if (e < N_EDGES) atomicAdd(&cnt[dst[e]], 1);
}

__global__ void k_scan1(const int* __restrict__ cnt, int* __restrict__ rowptr,
                        int* __restrict__ blocksum) {
    __shared__ int wsum[16];
    int tid = threadIdx.x;
    int gid = blockIdx.x * 1024 + tid;
    int lane = tid & 63, wid = tid >> 6;
    int v = (gid < N_NODES) ? cnt[gid] : 0;
    int incl = wave_incl_scan(v, lane);
    if (lane == 63) wsum[wid] = incl;
    __syncthreads();
    if (wid == 0) {
        int wv = (lane < 16) ? wsum[lane] : 0;
        int wincl = wave_incl_scan(wv, lane);
        if (lane < 16) wsum[lane] = wincl - wv;
    }
    __syncthreads();
    int excl = incl - v + wsum[wid];
    if (gid < N_NODES) rowptr[gid] = excl;
    if (tid == 1023) blocksum[blockIdx.x] = excl + v;
}

__global__ void k_scan2(int* __restrict__ blocksum) {
    int lane = threadIdx.x;
    int v = (lane < SCAN_NB) ? blocksum[lane] : 0;
    int incl = wave_incl_scan(v, lane);
    if (lane < SCAN_NB) blocksum[lane] = incl - v;
}

__global__ void k_scan3(int* __restrict__ rowptr, const int* __restrict__ blocksum,
                        int* __restrict__ cursor) {
    int tid = threadIdx.x;
    int gid = blockIdx.x * 1024 + tid;
    if (gid < N_NODES) {
        int r = rowptr[gid] + blocksum[blockIdx.x];
        rowptr[gid] = r;
        cursor[gid] = r;
    }
    if (blockIdx.x == 0 && tid == 0) rowptr[N_NODES] = N_EDGES;
}

__global__ void k_scatter(const int* __restrict__ src, const int* __restrict__ dst,
                          int* __restrict__ cursor, int* __restrict__ csr_src) {
    int e = blockIdx.x * 256 + threadIdx.x;
    if (e < N_EDGES) {
        int d = dst[e];
        int pos = atomicAdd(&cursor[d], 1);
        csr_src[pos] = src[e];
    }
}

// ---------------------------------------------------------------- weight f32 -> hi/lo bf16
struct WSrc {
    const float* s[7];
    int off[8];
};
__global__ void k_cvt_w(WSrc ws, ushort_t* __restrict__ hi, ushort_t* __restrict__ lo) {
    int gid = blockIdx.x * 256 + threadIdx.x;
    int stride = gridDim.x * 256;
#pragma unroll
    for (int mi = 0; mi < 7; mi++) {
        int n = ws.off[mi + 1] - ws.off[mi];
        const float* s = ws.s[mi];
        ushort_t* h = hi + ws.off[mi];
        ushort_t* l = lo + ws.off[mi];
        for (int i = gid; i < n; i += stride) {
            float f = s[i];
            ushort_t hb = f2bf(f);
            h[i] = hb;
            l[i] = f2bf(f - bf2f(hb));
        }
    }
}

// ---------------------------------------------------------------- dual projection via MFMA
// C[m][col] = sum_k A[m][k] * W[col][k] (+bias), col 0..63 -> xl (wl), 64..127 -> xr (wr)
// per block: 4 waves x 16 rows; per wave: 8 col-fragments of 16; mfma 16x16x32 bf16, hi+lo weights
template <int K, bool A_FP32>
__global__ void k_gemm_dual_mfma(const void* __restrict__ xa,
                                 const ushort_t* __restrict__ wlh, const ushort_t* __restrict__ wll,
                                 const ushort_t* __restrict__ wrh, const ushort_t* __restrict__ wrl,
                                 const float* __restrict__ bl, const float* __restrict__ br,
                                 ushort_t* __restrict__ xl, ushort_t* __restrict__ xr) {
    int tid = threadIdx.x;
    int wv = tid >> 6, lane = tid & 63;
    int m0 = blockIdx.x * 64 + wv * 16;
    if (m0 >= N_NODES) return;
    int arow = min(m0 + (lane & 15), N_NODES - 1);
    int koff = (lane >> 4) * 8;
    int wrow = lane & 15;  // within fragment

    float4v acc[8];
#pragma unroll
    for (int f = 0; f < 8; f++) acc[f] = (float4v)(0.f);

#pragma unroll
    for (int k0 = 0; k0 < K; k0 += 32) {
        short8v afrag;
        if (A_FP32) {
            const float* ap = (const float*)xa + (size_t)arow * K + k0 + koff;
            float4 a0 = *reinterpret_cast<const float4*>(ap);
            float4 a1 = *reinterpret_cast<const float4*>(ap + 4);
            afrag[0] = (short)f2bf(a0.x); afrag[1] = (short)f2bf(a0.y);
            afrag[2] = (short)f2bf(a0.z); afrag[3] = (short)f2bf(a0.w);
            afrag[4] = (short)f2bf(a1.x); afrag[5] = (short)f2bf(a1.y);
            afrag[6] = (short)f2bf(a1.z); afrag[7] = (short)f2bf(a1.w);
        } else {
            afrag = *reinterpret_cast<const short8v*>((const ushort_t*)xa + (size_t)arow * K + k0 + koff);
        }
#pragma unroll
        for (int f = 0; f < 8; f++) {
            const ushort_t* bh = (f < 4) ? wlh : wrh;
            const ushort_t* blo = (f < 4) ? wll : wrl;
            int row = ((f * 16 + wrow) & 63);
            size_t boff = (size_t)row * K + k0 + koff;
            short8v bfh = *reinterpret_cast<const short8v*>(bh + boff);
            short8v bfl = *reinterpret_cast<const short8v*>(blo + boff);
            acc[f] = __builtin_amdgcn_mfma_f32_16x16x32_bf16(afrag, bfh, acc[f], 0, 0, 0);
            acc[f] = __builtin_amdgcn_mfma_f32_16x16x32_bf16(afrag, bfl, acc[f], 0, 0, 0);
        }
    }

    int r0 = m0 + (lane >> 4) * 4;
#pragma unroll
    for (int f = 0; f < 8; f++) {
        int col = f * 16 + (lane & 15);
        float bias = (col < 64) ? bl[col] : br[col - 64];
        ushort_t* dstp = (col < 64) ? xl : xr;
        int c = col & 63;
#pragma unroll
        for (int j = 0; j < 4; j++) {
            int row = r0 + j;
            if (row < N_NODES) dstp[(size_t)row * 64 + c] = f2bf(acc[f][j] + bias);
        }
    }
}

// ---------------------------------------------------------------- h = relu(concat(x1,x2,x3) @ lin1_w.T + b), fp32 out
__global__ void k_gemm_h_mfma(const ushort_t* __restrict__ x1, const ushort_t* __restrict__ x2,
                              const ushort_t* __restrict__ x3,
                              const ushort_t* __restrict__ whi, const ushort_t* __restrict__ wlo,
                              const float* __restrict__ b, float* __restrict__ h) {
    int tid = threadIdx.x;
    int wv = tid >> 6, lane = tid & 63;
    int m0 = blockIdx.x * 64 + wv * 16;
    if (m0 >= N_NODES) return;
    int arow = min(m0 + (lane & 15), N_NODES - 1);
    int koff = (lane >> 4) * 8;
    int wrow = lane & 15;

    float4v acc[4];
#pragma unroll
    for (int f = 0; f < 4; f++) acc[f] = (float4v)(0.f);

#pragma unroll
    for (int ks = 0; ks < 6; ks++) {
        int k0 = ks * 32;
        const ushort_t* srcp = (ks < 2) ? x1 : (ks < 4 ? x2 : x3);
        int kc = k0 & 63;
        short8v afrag = *reinterpret_cast<const short8v*>(srcp + (size_t)arow * 64 + kc + koff);
#pragma unroll
        for (int f = 0; f < 4; f++) {
            size_t boff = (size_t)(f * 16 + wrow) * 192 + k0 + koff;
            short8v bfh = *reinterpret_cast<const short8v*>(whi + boff);
            short8v bfl = *reinterpret_cast<const short8v*>(wlo + boff);
            acc[f] = __builtin_amdgcn_mfma_f32_16x16x32_bf16(afrag, bfh, acc[f], 0, 0, 0);
            acc[f] = __builtin_amdgcn_mfma_f32_16x16x32_bf16(afrag, bfl, acc[f], 0, 0, 0);
        }
    }

    int r0 = m0 + (lane >> 4) * 4;
#pragma unroll
    for (int f = 0; f < 4; f++) {
        int col = f * 16 + (lane & 15);
        float bias = b[col];
#pragma unroll
        for (int j = 0; j < 4; j++) {
            int row = r0 + j;
            if (row < N_NODES) {
                float o = acc[f][j] + bias;
                h[(size_t)row * 64 + col] = o > 0.f ? o : 0.f;
            }
        }
    }
}

// ---------------------------------------------------------------- GATv2 aggregate: one wave per dst node
// bf16 features; transposed 4-edge multi-reduce + batched online softmax update
__global__ void k_gat(const ushort_t* __restrict__ xl, const ushort_t* __restrict__ xr,
                      const int* __restrict__ rowptr, const int* __restrict__ csr_src,
                      const float* __restrict__ att, const float* __restrict__ bo,
                      ushort_t* __restrict__ xout) {
    int wid = blockIdx.x * 4 + (threadIdx.x >> 6);
    int lane = threadIdx.x & 63;
    if (wid >= N_NODES) return;
    float attv = att[lane];
    float xrv = bf2f(xr[(size_t)wid * 64 + lane]);
    float xls = bf2f(xl[(size_t)wid * 64 + lane]);
    int beg = rowptr[wid], end = rowptr[wid + 1];

    float s = xls + xrv;
    float t = (s > 0.f ? s : LRELU_SLOPE * s) * attv;
    float m = wave_sum(t);
    float ssum = 1.0f;
    float acc = xls;

    bool b0 = (lane & 1) != 0;
    bool b1 = (lane & 2) != 0;

    int j = beg;
    for (; j + 4 <= end; j += 4) {
        int s0 = csr_src[j + 0], s1 = csr_src[j + 1];
        int s2 = csr_src[j + 2], s3 = csr_src[j + 3];
        float v0 = bf2f(xl[(size_t)s0 * 64 + lane]);
        float v1 = bf2f(xl[(size_t)s1 * 64 + lane]);
        float v2 = bf2f(xl[(size_t)s2 * 64 + lane]);
        float v3 = bf2f(xl[(size_t)s3 * 64 + lane]);
        float a0 = v0 + xrv, a1 = v1 + xrv, a2 = v2 + xrv, a3 = v3 + xrv;
        float t0 = (a0 > 0.f ? a0 : LRELU_SLOPE * a0) * attv;
        float t1 = (a1 > 0.f ? a1 : LRELU_SLOPE * a1) * attv;
        float t2 = (a2 > 0.f ? a2 : LRELU_SLOPE * a2) * attv;
        float t3 = (a3 > 0.f ? a3 : LRELU_SLOPE * a3) * attv;

        // fold 4 edges into lane classes (l&3), then one butterfly, then quad broadcast
        float c = (b0 ? t1 : t0) + __shfl_xor(b0 ? t0 : t1, 1);
        float d = (b0 ? t3 : t2) + __shfl_xor(b0 ? t2 : t3, 1);
        float e = (b1 ? d : c) + __shfl_xor(b1 ? c : d, 2);
        e += __shfl_xor(e, 4);
        e += __shfl_xor(e, 8);
        e += __shfl_xor(e, 16);
        e += __shfl_xor(e, 32);
        float f0 = e;                  // S_{idx}
        float f1 = __shfl_xor(e, 1);   // S_{idx^1}
        float f2 = __shfl_xor(e, 2);   // S_{idx^2}
        float f3 = __shfl_xor(f2, 1);  // S_{idx^3}

        float mn = fmaxf(fmaxf(fmaxf(f0, f1), fmaxf(f2, f3)), m);
        float sc = __expf(m - mn);
        float w0 = __expf(f0 - mn), w1 = __expf(f1 - mn);
        float w2 = __expf(f2 - mn), w3 = __expf(f3 - mn);
        ssum = ssum * sc + ((w0 + w1) + (w2 + w3));  // pair grouping lane-invariant

        // vp_k = v_{idx^k} so w_k pairs with its edge's feature
        float x01 = b0 ? v1 : v0, x01b = b0 ? v0 : v1;
        float x23 = b0 ? v3 : v2, x23b = b0 ? v2 : v3;
        float vp0 = b1 ? x23 : x01, vp2 = b1 ? x01 : x23;
        float vp1 = b1 ? x23b : x01b, vp3 = b1 ? x01b : x23b;
        acc = acc * sc + ((w0 * vp0 + w1 * vp1) + (w2 * vp2 + w3 * vp3));
        m = mn;
    }
    for (; j < end; j++) {
        int sj = csr_src[j];
        float v = bf2f(xl[(size_t)sj * 64 + lane]);
        float a = v + xrv;
        float tt = (a > 0.f ? a : LRELU_SLOPE * a) * attv;
        float e = wave_sum(tt);
        float mn = fmaxf(m, e);
        float sc = __expf(m - mn);
        float w = __expf(e - mn);
        ssum = ssum * sc + w;
        acc = acc * sc + w * v;
        m = mn;
    }

    float o = acc / (ssum + 1e-16f) + bo[lane];
    xout[(size_t)wid * 64 + lane] = f2bf(o > 0.f ? o : 0.f);
}

// ---------------------------------------------------------------- global_add_pool (batch_idx sorted)
__global__ void k_pool(const float* __restrict__ h, const int* __restrict__ batch,
                       float* __restrict__ g) {
    __shared__ float red[4][64];
    int base = blockIdx.x * 32;
    if (base >= N_NODES) return;
    int tid = threadIdx.x;
    int c = tid & 63;
    int rr = tid >> 6;
    int lastIdx = min(base + 31, N_NODES - 1);
    int b0 = batch[base];
    bool uniform = (batch[lastIdx] == b0);
    if (uniform) {
        float acc = 0.f;
        for (int r = rr; r < 32; r += 4) {
            int i = base + r;
            if (i < N_NODES) acc += h[(size_t)i * 64 + c];
        }
        red[rr][c] = acc;
        __syncthreads();
        if (rr == 0) {
            float sum = red[0][c] + red[1][c] + red[2][c] + red[3][c];
            atomicAdd(&g[b0 * 64 + c], sum);
        }
    } else {
        for (int r = rr; r < 32; r += 4) {
            int i = base + r;
            if (i < N_NODES) atomicAdd(&g[batch[i] * 64 + c], h[(size_t)i * 64 + c]);
        }
    }
}

// ---------------------------------------------------------------- head: one 64-thread block per graph
__global__ void k_head(const float* __restrict__ g, const float* __restrict__ pw,
                       const float* __restrict__ pb, const float* __restrict__ cw,
                       const float* __restrict__ cb, float* __restrict__ out) {
    int gb = blockIdx.x;
    int c = threadIdx.x;  // 0..63
    const float* gr = g + gb * 64;
    float a = pb[c];
    const float* pwr = pw + c * 64;
#pragma unroll
    for (int k = 0; k < 64; k++) a += gr[k] * pwr[k];
    a = a > 0.f ? a : 0.f;
    float o0 = wave_sum(a * cw[c]);
    float o1 = wave_sum(a * cw[64 + c]);
    if (c == 0) {
        out[gb * 2 + 0] = o0 + cb[0];
        out[gb * 2 + 1] = o1 + cb[1];
    }
}

// ---------------------------------------------------------------- launcher
extern "C" void kernel_launch(void* const* d_in, const int* in_sizes, int n_in,
                              void* d_out, int out_size, void* d_ws, size_t ws_size,
                              hipStream_t stream) {
    const float* x    = (const float*)d_in[0];
    const int*   ei   = (const int*)d_in[1];
    const int*   bidx = (const int*)d_in[2];
    const float* wl1 = (const float*)d_in[3],  *bl1 = (const float*)d_in[4];
    const float* wr1 = (const float*)d_in[5],  *br1 = (const float*)d_in[6];
    const float* att1 = (const float*)d_in[7], *bo1 = (const float*)d_in[8];
    const float* wl2 = (const float*)d_in[9],  *bl2 = (const float*)d_in[10];
    const float* wr2 = (const float*)d_in[11], *br2 = (const float*)d_in[12];
    const float* att2 = (const float*)d_in[13], *bo2 = (const float*)d_in[14];
    const float* wl3 = (const float*)d_in[15], *bl3 = (const float*)d_in[16];
    const float* wr3 = (const float*)d_in[17], *br3 = (const float*)d_in[18];
    const float* att3 = (const float*)d_in[19], *bo3 = (const float*)d_in[20];
    const float* lw = (const float*)d_in[21], *lb = (const float*)d_in[22];
    const float* pw = (const float*)d_in[23], *pb = (const float*)d_in[24];
    const float* cw = (const float*)d_in[25], *cb = (const float*)d_in[26];
    float* out = (float*)d_out;

    char* wsb = (char*)d_ws;
    size_t off = 0;
    auto alloc = [&](size_t bytes) {
        void* p = wsb + off;
        off = (off + bytes + 255) & ~(size_t)255;
        return p;
    };
    int* cnt      = (int*)alloc((size_t)N_NODES * 4);
    int* rowptr   = (int*)alloc((size_t)(N_NODES + 1) * 4);
    int* cursor   = (int*)alloc((size_t)N_NODES * 4);
    int* blocksum = (int*)alloc((size_t)SCAN_NB * 4);
    int* csr_src  = (int*)alloc((size_t)N_EDGES * 4);
    // weight hi/lo store: wl1(8192) wr1(8192) wl2(4096) wr2(4096) wl3(4096) wr3(4096) lin1(12288)
    const int woff[8] = {0, 8192, 16384, 20480, 24576, 28672, 32768, 45056};
    ushort_t* whi = (ushort_t*)alloc((size_t)45056 * 2);
    ushort_t* wlo = (ushort_t*)alloc((size_t)45056 * 2);
    ushort_t* xl   = (ushort_t*)alloc((size_t)N_NODES * 64 * 2);
    ushort_t* xrr  = (ushort_t*)alloc((size_t)N_NODES * 64 * 2);
    ushort_t* x1b  = (ushort_t*)alloc((size_t)N_NODES * 64 * 2);
    ushort_t* x2b  = (ushort_t*)alloc((size_t)N_NODES * 64 * 2);
    ushort_t* x3b  = (ushort_t*)alloc((size_t)N_NODES * 64 * 2);
    float* hb     = (float*)alloc((size_t)N_NODES * 64 * 4);
    float* g      = (float*)alloc((size_t)NGRAPH * 64 * 4);
    (void)ws_size; (void)in_sizes; (void)n_in; (void)out_size;

    const int* srcp = ei;
    const int* dstp = ei + N_EDGES;

    hipMemsetAsync(cnt, 0, (size_t)N_NODES * 4, stream);
    hipMemsetAsync(g, 0, (size_t)NGRAPH * 64 * 4, stream);

    k_hist<<<N_EDGES / 256, 256, 0, stream>>>(dstp, cnt);
    k_scan1<<<SCAN_NB, 1024, 0, stream>>>(cnt, rowptr, blocksum);
    k_scan2<<<1, 64, 0, stream>>>(blocksum);
    k_scan3<<<SCAN_NB, 1024, 0, stream>>>(rowptr, blocksum, cursor);
    k_scatter<<<N_EDGES / 256, 256, 0, stream>>>(srcp, dstp, cursor, csr_src);

    WSrc ws;
    ws.s[0] = wl1; ws.s[1] = wr1; ws.s[2] = wl2; ws.s[3] = wr2;
    ws.s[4] = wl3; ws.s[5] = wr3; ws.s[6] = lw;
    for (int i = 0; i < 8; i++) ws.off[i] = woff[i];
    k_cvt_w<<<64, 256, 0, stream>>>(ws, whi, wlo);

    int gemmBlocks = (N_NODES + 63) / 64;
    int gatBlocks = (N_NODES + 3) / 4;

    // layer 1 (A = x fp32, K=128)
    k_gemm_dual_mfma<128, true><<<gemmBlocks, 256, 0, stream>>>(
        x, whi + woff[0], wlo + woff[0], whi + woff[1], wlo + woff[1], bl1, br1, xl, xrr);
    k_gat<<<gatBlocks, 256, 0, stream>>>(xl, xrr, rowptr, csr_src, att1, bo1, x1b);
    // layer 2 (A = x1b bf16, K=64)
    k_gemm_dual_mfma<64, false><<<gemmBlocks, 256, 0, stream>>>(
        x1b, whi + woff[2], wlo + woff[2], whi + woff[3], wlo + woff[3], bl2, br2, xl, xrr);
    k_gat<<<gatBlocks, 256, 0, stream>>>(xl, xrr, rowptr, csr_src, att2, bo2, x2b);
    // layer 3
    k_gemm_dual_mfma<64, false><<<gemmBlocks, 256, 0, stream>>>(
        x2b, whi + woff[4], wlo + woff[4], whi + woff[5], wlo + woff[5], bl3, br3, xl, xrr);
    k_gat<<<gatBlocks, 256, 0, stream>>>(xl, xrr, rowptr, csr_src, att3, bo3, x3b);

    // head
    k_gemm_h_mfma<<<gemmBlocks, 256, 0, stream>>>(x1b, x2b, x3b, whi + woff[6], wlo + woff[6], lb, hb);
    k_pool<<<(N_NODES + 31) / 32, 256, 0, stream>>>(hb, bidx, g);
    k_head<<<NGRAPH, 64, 0, stream>>>(g, pw, pb, cw, cb, out);
}